// Round 3
// baseline (341.170 us; speedup 1.0000x reference)
//
#include <hip/hip_runtime.h>

using half8   = __attribute__((ext_vector_type(8))) _Float16;
using floatx4 = __attribute__((ext_vector_type(4))) float;
using floatx2 = __attribute__((ext_vector_type(2))) float;
using short8  = __attribute__((ext_vector_type(8))) short;

// xt layout: [b 32][cchunk 8][hh 58][ww 64][slot 40] f16  (80 B per position,
// slots 32..39 zero pad -> read bank-quad (5*pos+quad)%8 is a permutation).
// hh = h+1 (rows 0,57 zero), ww = w+1 (cols 0,57..63 zero).
#define XT_ROW_ELEMS 2560                       // 64*40
#define XT_ROW_BYTES 5120
#define XT_OFF ((size_t)2 << 20)                // wre in [0, 1.18MB); xt at +2MB
#define XT_BYTES ((size_t)256 * 58 * XT_ROW_BYTES)   // 76,021,760

__device__ __forceinline__ void dma16(const void* g, void* l) {
  __builtin_amdgcn_global_load_lds(
      (const __attribute__((address_space(1))) void*)g,
      (__attribute__((address_space(3))) void*)l, 16, 0, 0);
}

// ---- prep: fused weight repack + x transpose/convert/pad ----
// blocks [0,14848): transpose one (b,cc,hh) row; blocks [14848,17152): repack
__global__ __launch_bounds__(256) void prep_kernel(
    const float* __restrict__ x, const float* __restrict__ qw,
    _Float16* __restrict__ wre, _Float16* __restrict__ xt)
{
  const int bid = blockIdx.x;
  const int t = threadIdx.x;
  if (bid >= 14848) {                           // ---- weight repack ----
    int idx = (bid - 14848) * 256 + t;          // < 9*256*256
    int c = idx & 255, co = (idx >> 8) & 255, s = idx >> 16;
    wre[idx] = (_Float16)qw[(co * 256 + c) * 9 + s];
    return;
  }
  // ---- transpose one padded row ----
  __shared__ _Float16 lt[32 * 57];              // [c32][w56 +1 pad]
  const int hh = bid % 58;
  const int bc = bid / 58;                      // b*8 + cc
  const int cc = bc & 7, b = bc >> 3;
  _Float16* dst = xt + ((size_t)bc * 58 + hh) * XT_ROW_ELEMS;
  const bool interior = (hh >= 1) && (hh <= 56);
  if (interior) {
    const int c = t >> 3, j = t & 7;            // 8 threads cover 56 w
    const float* src = x + (((size_t)(b * 256 + cc * 32 + c)) * 56 + (hh - 1)) * 56 + j * 7;
#pragma unroll
    for (int i = 0; i < 7; ++i) lt[c * 57 + j * 7 + i] = (_Float16)src[i];
  }
  __syncthreads();
  // write 320 16B-chunks (64 pos x 5 slots-of-8) coalesced
  for (int ch = t; ch < 320; ch += 256) {
    int pos = ch / 5, sl = ch - pos * 5;
    short8 v = {0, 0, 0, 0, 0, 0, 0, 0};
    if (interior && sl < 4 && pos >= 1 && pos <= 56) {
      int w = pos - 1;
#pragma unroll
      for (int i = 0; i < 8; ++i)
        v[i] = __builtin_bit_cast(short, lt[(sl * 8 + i) * 57 + w]);
    }
    *reinterpret_cast<short8*>(dst + ch * 8) = v;
  }
}

// ---- main conv v3: DMA-staged, m=32/wave, 4 blocks/CU resident ----
// Block: 256 thr = 4 waves; computes 128 cout x 112 px (2 rows x 56).
// Grid: 1792 = (b 32)(hpair 28)(cohalf 2). Wave: 32 cout (acc[2][7] = 56 AGPR).
// 4 resident blocks x 40960 B LDS = exactly 160 KiB/CU.
__global__ __launch_bounds__(256, 4) void binconv_v3(
    const float* __restrict__ scale, const float* __restrict__ bias,
    const _Float16* __restrict__ wre, const _Float16* __restrict__ xt,
    float* __restrict__ out)
{
  __shared__ _Float16 xs[2 * 4 * 64 * 40];      // 2 x 20,480 B

  const int tid    = threadIdx.x;
  const int bid    = blockIdx.x;
  const int cohalf = bid & 1;
  const int nb     = bid >> 1;                  // (b, h-pair)
  const int b      = nb / 28;
  const int h0     = (nb % 28) * 2;
  const int wave   = tid >> 6;
  const int lane   = tid & 63;
  const int nl     = lane & 15;
  const int quad   = lane >> 4;
  const int co_wave = cohalf * 128 + wave * 32;

  int bbase[7];                                 // byte offsets, 80B/pos stride
#pragma unroll
  for (int j = 0; j < 7; ++j) {
    int n = j * 16 + nl;
    int r = (n >= 56) ? 1 : 0;
    int w = n - r * 56;
    bbase[j] = (r * 64 + w) * 80 + quad * 16;
  }

  const _Float16* aptr[2];
#pragma unroll
  for (int mi = 0; mi < 2; ++mi)
    aptr[mi] = wre + (co_wave + mi * 16 + nl) * 256 + quad * 8;

  floatx4 acc[2][7];
#pragma unroll
  for (int mi = 0; mi < 2; ++mi)
#pragma unroll
    for (int j = 0; j < 7; ++j)
      acc[mi][j] = (floatx4){0.f, 0.f, 0.f, 0.f};

  // staging: wave handles padded row hh = h0 + wave (always in-bounds 0..57)
  const char* xsrc = (const char*)(xt + ((size_t)(b * 8) * 58 + h0) * XT_ROW_ELEMS);
  const int wlane = wave * XT_ROW_BYTES + lane * 16;
  const int wldso = wave * XT_ROW_BYTES;

  // prologue: DMA chunk 0 -> buf 0
#pragma unroll
  for (int i = 0; i < 5; ++i)
    dma16(xsrc + wlane + i * 1024, (char*)xs + wldso + i * 1024);

  int bufoff = 0;
  for (int cc = 0; cc < 8; ++cc) {
    __syncthreads();                            // drains this chunk's DMA
    if (cc < 7) {                               // prefetch next chunk
      const char* srcn = xsrc + (size_t)(cc + 1) * (58 * XT_ROW_BYTES);
#pragma unroll
      for (int i = 0; i < 5; ++i)
        dma16(srcn + wlane + i * 1024,
              (char*)xs + (bufoff ^ 20480) + wldso + i * 1024);
    }
    const int c0 = cc * 32;
    const char* xb = (const char*)xs + bufoff;
    __builtin_amdgcn_s_setprio(1);
#pragma unroll
    for (int s = 0; s < 9; ++s) {
      const int kh = s / 3, kw = s - kh * 3;
      half8 a[2];
#pragma unroll
      for (int mi = 0; mi < 2; ++mi)
        a[mi] = *reinterpret_cast<const half8*>(aptr[mi] + s * 65536 + c0);
      const int soff = (kh * 64 + kw) * 80;
#pragma unroll
      for (int j = 0; j < 7; ++j) {
        half8 bf = *reinterpret_cast<const half8*>(xb + bbase[j] + soff);
#pragma unroll
        for (int mi = 0; mi < 2; ++mi)
          acc[mi][j] = __builtin_amdgcn_mfma_f32_16x16x32_f16(a[mi], bf, acc[mi][j], 0, 0, 0);
      }
    }
    __builtin_amdgcn_s_setprio(0);
    bufoff ^= 20480;
  }

  // epilogue: C/D layout n=lane&15, m=quad*4+reg
#pragma unroll
  for (int mi = 0; mi < 2; ++mi) {
#pragma unroll
    for (int reg = 0; reg < 4; ++reg) {
      int co = co_wave + mi * 16 + quad * 4 + reg;
      float s_ = scale[co];
      float bi = bias[co];
#pragma unroll
      for (int j = 0; j < 7; ++j) {
        int n = j * 16 + nl;
        int r = (n >= 56) ? 1 : 0;
        int w = n - r * 56;
        out[(((size_t)b * 256 + co) * 56 + (h0 + r)) * 56 + w] =
            acc[mi][j][reg] * s_ + bi;
      }
    }
  }
}

// ---------------- fallback path (ws too small): fused kernel ----------------
__global__ void repack_weights(const float* __restrict__ qw,
                               _Float16* __restrict__ wre, int n) {
  int t = blockIdx.x * 256 + threadIdx.x;
  if (t >= n) return;
  int c = t & 255, co = (t >> 8) & 255, s = t >> 16;
  wre[t] = (_Float16)qw[(co * 256 + c) * 9 + s];
}

__global__ __launch_bounds__(512, 4) void binconv_fused(
    const float* __restrict__ x, const float* __restrict__ scale,
    const float* __restrict__ bias, const _Float16* __restrict__ wre,
    float* __restrict__ out)
{
  __shared__ _Float16 xs[2 * 4 * 64 * 40];
  const int tid  = threadIdx.x;
  const int nb   = blockIdx.x;
  const int b    = nb / 28;
  const int h0   = (nb % 28) * 2;
  const int wave = tid >> 6;
  const int lane = tid & 63;
  const int nl   = lane & 15;
  const int quad = lane >> 4;
  const int co_wave = wave * 32;
  {
    short8 z = {0, 0, 0, 0, 0, 0, 0, 0};
    short8* xs8 = reinterpret_cast<short8*>(xs);
#pragma unroll
    for (int i = 0; i < 5; ++i) xs8[tid + i * 512] = z;
  }
  const int r     = wave >> 1;
  const int chalf = wave & 1;
  const int sc    = lane & 15;
  const int q     = lane >> 4;
  const int ch    = chalf * 16 + sc;
  const int w0    = q * 14;
  const int h     = h0 + r - 1;
  const bool hok  = (h >= 0) && (h < 56);
  const float* xc = x + (((size_t)b * 256 + ch) * 56 + (hok ? h : 0)) * 56 + w0;
  _Float16* const wrow = xs + r * 2560 + ch;
  floatx2 va[7];
  int bbase[7];
#pragma unroll
  for (int j = 0; j < 7; ++j) {
    int n = j * 16 + nl;
    int rr = (n >= 56) ? 1 : 0;
    int w = n - rr * 56;
    bbase[j] = (rr * 64 + w) * 80 + quad * 16;
  }
  const _Float16* aptr[2];
#pragma unroll
  for (int mi = 0; mi < 2; ++mi)
    aptr[mi] = wre + (co_wave + mi * 16 + nl) * 256 + quad * 8;
  floatx4 acc[2][7];
#pragma unroll
  for (int mi = 0; mi < 2; ++mi)
#pragma unroll
    for (int j = 0; j < 7; ++j)
      acc[mi][j] = (floatx4){0.f, 0.f, 0.f, 0.f};
  __syncthreads();
  if (hok) {
#pragma unroll
    for (int i = 0; i < 7; ++i)
      va[i] = *reinterpret_cast<const floatx2*>(xc + 2 * i);
#pragma unroll
    for (int i = 0; i < 7; ++i) {
      wrow[(w0 + 2 * i + 1) * 40] = (_Float16)va[i][0];
      wrow[(w0 + 2 * i + 2) * 40] = (_Float16)va[i][1];
    }
  }
  int bufe = 0;
  for (int cc = 0; cc < 8; ++cc) {
    __syncthreads();
    if (cc < 7 && hok) {
      const float* A = xc + (size_t)(cc + 1) * 100352;
#pragma unroll
      for (int i = 0; i < 7; ++i)
        va[i] = *reinterpret_cast<const floatx2*>(A + 2 * i);
    }
    const int c0 = cc * 32;
    const char* xb = reinterpret_cast<const char*>(xs) + bufe * 2;
#pragma unroll
    for (int s = 0; s < 9; ++s) {
      const int kh = s / 3, kw = s - kh * 3;
      half8 a[2];
#pragma unroll
      for (int mi = 0; mi < 2; ++mi)
        a[mi] = *reinterpret_cast<const half8*>(aptr[mi] + s * 65536 + c0);
      const int soff = (kh * 64 + kw) * 80;
#pragma unroll
      for (int j = 0; j < 7; ++j) {
        half8 bf = *reinterpret_cast<const half8*>(xb + bbase[j] + soff);
#pragma unroll
        for (int mi = 0; mi < 2; ++mi)
          acc[mi][j] = __builtin_amdgcn_mfma_f32_16x16x32_f16(a[mi], bf, acc[mi][j], 0, 0, 0);
      }
    }
    if (cc < 7 && hok) {
      _Float16* d = wrow + (bufe ^ 10240);
#pragma unroll
      for (int i = 0; i < 7; ++i) {
        d[(w0 + 2 * i + 1) * 40] = (_Float16)va[i][0];
        d[(w0 + 2 * i + 2) * 40] = (_Float16)va[i][1];
      }
    }
    bufe ^= 10240;
  }
#pragma unroll
  for (int mi = 0; mi < 2; ++mi) {
#pragma unroll
    for (int reg = 0; reg < 4; ++reg) {
      int co = co_wave + mi * 16 + quad * 4 + reg;
      float s_ = scale[co];
      float bi = bias[co];
#pragma unroll
      for (int j = 0; j < 7; ++j) {
        int n = j * 16 + nl;
        int rr = (n >= 56) ? 1 : 0;
        int w = n - rr * 56;
        out[(((size_t)b * 256 + co) * 56 + (h0 + rr)) * 56 + w] =
            acc[mi][j][reg] * s_ + bi;
      }
    }
  }
}

extern "C" void kernel_launch(void* const* d_in, const int* in_sizes, int n_in,
                              void* d_out, int out_size, void* d_ws, size_t ws_size,
                              hipStream_t stream) {
  const float* x     = (const float*)d_in[0];   // [32,256,56,56]
  const float* scale = (const float*)d_in[1];   // [256]
  const float* qw    = (const float*)d_in[2];   // [256,256,3,3] in {-1,0,1}
  const float* bias  = (const float*)d_in[3];   // [256]
  float* out = (float*)d_out;

  _Float16* wre = (_Float16*)d_ws;

  if (ws_size >= XT_OFF + XT_BYTES) {
    _Float16* xt = (_Float16*)((char*)d_ws + XT_OFF);
    prep_kernel<<<17152, 256, 0, stream>>>(x, qw, wre, xt);
    binconv_v3<<<1792, 256, 0, stream>>>(scale, bias, wre, xt, out);
  } else {
    repack_weights<<<2304, 256, 0, stream>>>(qw, wre, 9 * 256 * 256);
    binconv_fused<<<896, 512, 0, stream>>>(x, scale, bias, wre, out);
  }
}

// Round 5
// 329.598 us; speedup vs baseline: 1.0351x; 1.0351x over previous
//
#include <hip/hip_runtime.h>

using half8   = __attribute__((ext_vector_type(8))) _Float16;
using floatx4 = __attribute__((ext_vector_type(4))) float;
using floatx2 = __attribute__((ext_vector_type(2))) float;
using short8  = __attribute__((ext_vector_type(8))) short;

// xt layout: [b 32][cchunk 8][hh 58][ww 64][slot 40] f16  (80 B per position,
// slots 32..39 zero pad -> read bank-quad (5*pos+quad)%8 is a permutation).
// hh = h+1 (rows 0,57 zero), ww = w+1 (cols 0,57..63 zero).
#define XT_ROW_ELEMS 2560                       // 64*40
#define XT_ROW_BYTES 5120
#define XT_OFF ((size_t)2 << 20)                // wre in [0, 1.18MB); xt at +2MB
#define XT_BYTES ((size_t)256 * 58 * XT_ROW_BYTES)   // 76,021,760

__device__ __forceinline__ void dma16(const void* g, void* l) {
  __builtin_amdgcn_global_load_lds(
      (const __attribute__((address_space(1))) void*)g,
      (__attribute__((address_space(3))) void*)l, 16, 0, 0);
}

// ---- prep: fused weight repack + x transpose/convert/pad ----
// blocks [0,14848): transpose one (b,cc,hh) row; blocks [14848,17152): repack
__global__ __launch_bounds__(256) void prep_kernel(
    const float* __restrict__ x, const float* __restrict__ qw,
    _Float16* __restrict__ wre, _Float16* __restrict__ xt)
{
  const int bid = blockIdx.x;
  const int t = threadIdx.x;
  if (bid >= 14848) {                           // ---- weight repack ----
    int idx = (bid - 14848) * 256 + t;          // < 9*256*256
    int c = idx & 255, co = (idx >> 8) & 255, s = idx >> 16;
    wre[idx] = (_Float16)qw[(co * 256 + c) * 9 + s];
    return;
  }
  // ---- transpose one padded row ----
  __shared__ _Float16 lt[32 * 57];              // [c32][w56 +1 pad]
  const int hh = bid % 58;
  const int bc = bid / 58;                      // b*8 + cc
  const int cc = bc & 7, b = bc >> 3;
  _Float16* dst = xt + ((size_t)bc * 58 + hh) * XT_ROW_ELEMS;
  const bool interior = (hh >= 1) && (hh <= 56);
  if (interior) {
    const int c = t >> 3, j = t & 7;            // 8 threads cover 56 w
    const float* src = x + (((size_t)(b * 256 + cc * 32 + c)) * 56 + (hh - 1)) * 56 + j * 7;
#pragma unroll
    for (int i = 0; i < 7; ++i) lt[c * 57 + j * 7 + i] = (_Float16)src[i];
  }
  __syncthreads();
  // write 320 16B-chunks (64 pos x 5 slots-of-8) coalesced
  for (int ch = t; ch < 320; ch += 256) {
    int pos = ch / 5, sl = ch - pos * 5;
    short8 v = {0, 0, 0, 0, 0, 0, 0, 0};
    if (interior && sl < 4 && pos >= 1 && pos <= 56) {
      int w = pos - 1;
#pragma unroll
      for (int i = 0; i < 8; ++i)
        v[i] = __builtin_bit_cast(short, lt[(sl * 8 + i) * 57 + w]);
    }
    *reinterpret_cast<short8*>(dst + ch * 8) = v;
  }
}

// ---- main conv v4: mi=4, DMA-staged, explicit A/B software pipeline ----
// Block: 256 thr = 4 waves; 256 cout x 112 px (2 rows x 56). Grid 896.
// Wave: 64 cout (acc[4][7] = 112 AGPR). 2 blocks/CU (reg-bound).
// Inner loop: consume acur/bcur while issuing bnxt (next s ds_reads) and
// anxt (next step A-loads, pipelined ACROSS chunk boundaries so the
// first A-consume of a chunk never forces the prefetch-DMA drain).
__global__ __launch_bounds__(256, 2) void binconv_v4(
    const float* __restrict__ scale, const float* __restrict__ bias,
    const _Float16* __restrict__ wre, const _Float16* __restrict__ xt,
    float* __restrict__ out)
{
  __shared__ _Float16 xs[2 * 4 * 64 * 40];      // 2 x 20,480 B

  const int tid  = threadIdx.x;
  const int nb   = blockIdx.x;                  // (b, h-pair)
  const int b    = nb / 28;
  const int h0   = (nb % 28) * 2;
  const int wave = tid >> 6;
  const int lane = tid & 63;
  const int nl   = lane & 15;
  const int quad = lane >> 4;
  const int co_wave = wave * 64;

  int bbase[7];                                 // byte offsets, 80B/pos stride
#pragma unroll
  for (int j = 0; j < 7; ++j) {
    int n = j * 16 + nl;
    int r = (n >= 56) ? 1 : 0;
    int w = n - r * 56;
    bbase[j] = (r * 64 + w) * 80 + quad * 16;
  }

  const _Float16* aptr[4];
#pragma unroll
  for (int mi = 0; mi < 4; ++mi)
    aptr[mi] = wre + (co_wave + mi * 16 + nl) * 256 + quad * 8;

  floatx4 acc[4][7];
#pragma unroll
  for (int mi = 0; mi < 4; ++mi)
#pragma unroll
    for (int j = 0; j < 7; ++j)
      acc[mi][j] = (floatx4){0.f, 0.f, 0.f, 0.f};

  // staging: wave handles padded row hh = h0 + wave (always in-bounds 0..57)
  const char* xsrc = (const char*)(xt + ((size_t)(b * 8) * 58 + h0) * XT_ROW_ELEMS);
  const int wlane = wave * XT_ROW_BYTES + lane * 16;
  const int wldso = wave * XT_ROW_BYTES;

  // prologue: DMA chunk 0 -> buf 0 (issued before any A-load so A-waits
  // never gate on it; the first barrier drains it anyway)
#pragma unroll
  for (int i = 0; i < 5; ++i)
    dma16(xsrc + wlane + i * 1024, (char*)xs + wldso + i * 1024);

  half8 acur[4], anxt[4];
#pragma unroll
  for (int mi = 0; mi < 4; ++mi)                // A(chunk0, s=0)
    acur[mi] = *reinterpret_cast<const half8*>(aptr[mi]);

  int bufoff = 0;
  for (int cc = 0; cc < 8; ++cc) {
    __syncthreads();                            // drains this chunk's DMA
    if (cc < 7) {                               // prefetch next chunk
      const char* srcn = xsrc + (size_t)(cc + 1) * (58 * XT_ROW_BYTES);
#pragma unroll
      for (int i = 0; i < 5; ++i)
        dma16(srcn + wlane + i * 1024,
              (char*)xs + (bufoff ^ 20480) + wldso + i * 1024);
    }
    const int c0 = cc * 32;
    const char* xb = (const char*)xs + bufoff;

    half8 bcur[7], bnxt[7];
#pragma unroll
    for (int j = 0; j < 7; ++j)                 // B(s=0): soff(0)=0
      bcur[j] = *reinterpret_cast<const half8*>(xb + bbase[j]);

#pragma unroll
    for (int s = 0; s < 9; ++s) {
      // issue next-s B fragments (hide ds latency under MFMA cluster)
      if (s < 8) {
        const int kh1 = (s + 1) / 3, kw1 = (s + 1) - kh1 * 3;
        const int soff1 = (kh1 * 64 + kw1) * 80;
#pragma unroll
        for (int j = 0; j < 7; ++j)
          bnxt[j] = *reinterpret_cast<const half8*>(xb + bbase[j] + soff1);
      }
      // issue next-step A fragments (crosses chunk boundary at s=8)
      if (cc < 7 || s < 8) {
        const int s1 = (s < 8) ? s + 1 : 0;
        const int c1 = (s < 8) ? c0 : c0 + 32;
#pragma unroll
        for (int mi = 0; mi < 4; ++mi)
          anxt[mi] = *reinterpret_cast<const half8*>(aptr[mi] + s1 * 65536 + c1);
      }
      __builtin_amdgcn_s_setprio(1);
#pragma unroll
      for (int j = 0; j < 7; ++j)
#pragma unroll
        for (int mi = 0; mi < 4; ++mi)
          acc[mi][j] = __builtin_amdgcn_mfma_f32_16x16x32_f16(acur[mi], bcur[j], acc[mi][j], 0, 0, 0);
      __builtin_amdgcn_s_setprio(0);
      // rotate pipeline registers (all static under full unroll)
#pragma unroll
      for (int mi = 0; mi < 4; ++mi) acur[mi] = anxt[mi];
#pragma unroll
      for (int j = 0; j < 7; ++j) bcur[j] = bnxt[j];
    }
    bufoff ^= 20480;
  }

  // epilogue: C/D layout n=lane&15, m=quad*4+reg
#pragma unroll
  for (int mi = 0; mi < 4; ++mi) {
#pragma unroll
    for (int reg = 0; reg < 4; ++reg) {
      int co = co_wave + mi * 16 + quad * 4 + reg;
      float s_ = scale[co];
      float bi = bias[co];
#pragma unroll
      for (int j = 0; j < 7; ++j) {
        int n = j * 16 + nl;
        int r = (n >= 56) ? 1 : 0;
        int w = n - r * 56;
        out[(((size_t)b * 256 + co) * 56 + (h0 + r)) * 56 + w] =
            acc[mi][j][reg] * s_ + bi;
      }
    }
  }
}

// ---------------- fallback path (ws too small): fused kernel ----------------
__global__ void repack_weights(const float* __restrict__ qw,
                               _Float16* __restrict__ wre, int n) {
  int t = blockIdx.x * 256 + threadIdx.x;
  if (t >= n) return;
  int c = t & 255, co = (t >> 8) & 255, s = t >> 16;
  wre[t] = (_Float16)qw[(co * 256 + c) * 9 + s];
}

__global__ __launch_bounds__(512, 4) void binconv_fused(
    const float* __restrict__ x, const float* __restrict__ scale,
    const float* __restrict__ bias, const _Float16* __restrict__ wre,
    float* __restrict__ out)
{
  __shared__ _Float16 xs[2 * 4 * 64 * 40];
  const int tid  = threadIdx.x;
  const int nb   = blockIdx.x;
  const int b    = nb / 28;
  const int h0   = (nb % 28) * 2;
  const int wave = tid >> 6;
  const int lane = tid & 63;
  const int nl   = lane & 15;
  const int quad = lane >> 4;
  const int co_wave = wave * 32;
  {
    short8 z = {0, 0, 0, 0, 0, 0, 0, 0};
    short8* xs8 = reinterpret_cast<short8*>(xs);
#pragma unroll
    for (int i = 0; i < 5; ++i) xs8[tid + i * 512] = z;
  }
  const int r     = wave >> 1;
  const int chalf = wave & 1;
  const int sc    = lane & 15;
  const int q     = lane >> 4;
  const int ch    = chalf * 16 + sc;
  const int w0    = q * 14;
  const int h     = h0 + r - 1;
  const bool hok  = (h >= 0) && (h < 56);
  const float* xc = x + (((size_t)b * 256 + ch) * 56 + (hok ? h : 0)) * 56 + w0;
  _Float16* const wrow = xs + r * 2560 + ch;
  floatx2 va[7];
  int bbase[7];
#pragma unroll
  for (int j = 0; j < 7; ++j) {
    int n = j * 16 + nl;
    int rr = (n >= 56) ? 1 : 0;
    int w = n - rr * 56;
    bbase[j] = (rr * 64 + w) * 80 + quad * 16;
  }
  const _Float16* aptr[2];
#pragma unroll
  for (int mi = 0; mi < 2; ++mi)
    aptr[mi] = wre + (co_wave + mi * 16 + nl) * 256 + quad * 8;
  floatx4 acc[2][7];
#pragma unroll
  for (int mi = 0; mi < 2; ++mi)
#pragma unroll
    for (int j = 0; j < 7; ++j)
      acc[mi][j] = (floatx4){0.f, 0.f, 0.f, 0.f};
  __syncthreads();
  if (hok) {
#pragma unroll
    for (int i = 0; i < 7; ++i)
      va[i] = *reinterpret_cast<const floatx2*>(xc + 2 * i);
#pragma unroll
    for (int i = 0; i < 7; ++i) {
      wrow[(w0 + 2 * i + 1) * 40] = (_Float16)va[i][0];
      wrow[(w0 + 2 * i + 2) * 40] = (_Float16)va[i][1];
    }
  }
  int bufe = 0;
  for (int cc = 0; cc < 8; ++cc) {
    __syncthreads();
    if (cc < 7 && hok) {
      const float* A = xc + (size_t)(cc + 1) * 100352;
#pragma unroll
      for (int i = 0; i < 7; ++i)
        va[i] = *reinterpret_cast<const floatx2*>(A + 2 * i);
    }
    const int c0 = cc * 32;
    const char* xb = reinterpret_cast<const char*>(xs) + bufe * 2;
#pragma unroll
    for (int s = 0; s < 9; ++s) {
      const int kh = s / 3, kw = s - kh * 3;
      half8 a[2];
#pragma unroll
      for (int mi = 0; mi < 2; ++mi)
        a[mi] = *reinterpret_cast<const half8*>(aptr[mi] + s * 65536 + c0);
      const int soff = (kh * 64 + kw) * 80;
#pragma unroll
      for (int j = 0; j < 7; ++j) {
        half8 bf = *reinterpret_cast<const half8*>(xb + bbase[j] + soff);
#pragma unroll
        for (int mi = 0; mi < 2; ++mi)
          acc[mi][j] = __builtin_amdgcn_mfma_f32_16x16x32_f16(a[mi], bf, acc[mi][j], 0, 0, 0);
      }
    }
    if (cc < 7 && hok) {
      _Float16* d = wrow + (bufe ^ 10240);
#pragma unroll
      for (int i = 0; i < 7; ++i) {
        d[(w0 + 2 * i + 1) * 40] = (_Float16)va[i][0];
        d[(w0 + 2 * i + 2) * 40] = (_Float16)va[i][1];
      }
    }
    bufe ^= 10240;
  }
#pragma unroll
  for (int mi = 0; mi < 2; ++mi) {
#pragma unroll
    for (int reg = 0; reg < 4; ++reg) {
      int co = co_wave + mi * 16 + quad * 4 + reg;
      float s_ = scale[co];
      float bi = bias[co];
#pragma unroll
      for (int j = 0; j < 7; ++j) {
        int n = j * 16 + nl;
        int rr = (n >= 56) ? 1 : 0;
        int w = n - rr * 56;
        out[(((size_t)b * 256 + co) * 56 + (h0 + rr)) * 56 + w] =
            acc[mi][j][reg] * s_ + bi;
      }
    }
  }
}

extern "C" void kernel_launch(void* const* d_in, const int* in_sizes, int n_in,
                              void* d_out, int out_size, void* d_ws, size_t ws_size,
                              hipStream_t stream) {
  const float* x     = (const float*)d_in[0];   // [32,256,56,56]
  const float* scale = (const float*)d_in[1];   // [256]
  const float* qw    = (const float*)d_in[2];   // [256,256,3,3] in {-1,0,1}
  const float* bias  = (const float*)d_in[3];   // [256]
  float* out = (float*)d_out;

  _Float16* wre = (_Float16*)d_ws;

  if (ws_size >= XT_OFF + XT_BYTES) {
    _Float16* xt = (_Float16*)((char*)d_ws + XT_OFF);
    prep_kernel<<<17152, 256, 0, stream>>>(x, qw, wre, xt);
    binconv_v4<<<896, 256, 0, stream>>>(scale, bias, wre, xt, out);
  } else {
    repack_weights<<<2304, 256, 0, stream>>>(qw, wre, 9 * 256 * 256);
    binconv_fused<<<896, 512, 0, stream>>>(x, scale, bias, wre, out);
  }
}